// Round 1
// baseline (209.124 us; speedup 1.0000x reference)
//
#include <hip/hip_runtime.h>
#include <hip/hip_bf16.h>

#define NCOL 10752   // 512*21
#define NROW 2048
#define NG 15
#define NTILES 23

typedef __bf16 bf16;
typedef __attribute__((ext_vector_type(8))) __bf16 bf16x8;
typedef __attribute__((ext_vector_type(4))) __bf16 bf16x4;
typedef __attribute__((ext_vector_type(4))) float f32x4;

__constant__ int c_gsize[NG]  = {64,128,256,96,160,224,192,288,320,112,80,48,32,16,32};
__constant__ int c_gstart[NG] = {0,64,192,448,544,704,928,1120,1408,1728,1840,1920,1968,2000,2016};
__constant__ int c_tgrp[NTILES] = {0,1,2,2,3,4,4,5,5,6,6,7,7,7,8,8,8,9,10,11,12,13,14};
__constant__ int c_trow[NTILES] = {0,0,0,128,0,0,128,0,128,0,128,0,128,256,0,128,256,0,0,0,0,0,0};

struct MatPtrs { const float* p[NG]; };

constexpr int BM = 128, BN = 128, BK = 32, BKp = 40;

__global__ __launch_bounds__(256)
void matapply_kernel(const float* __restrict__ x, MatPtrs mats, float* __restrict__ out)
{
    __shared__ bf16 sA[BM][BKp];   // M tile: [row][k]
    __shared__ bf16 sB[BN][BKp];   // X tile transposed: [col][k], k XOR-swizzled

    const int tid    = threadIdx.x;
    const int tileid = blockIdx.x;           // row-tile id (fastest-varying for L2 X reuse)
    const int colb   = blockIdx.y * BN;

    const int grp  = c_tgrp[tileid];
    const int row0 = c_trow[tileid];
    const int g    = c_gsize[grp];
    const int s    = c_gstart[grp];
    const float* __restrict__ M = mats.p[grp];

    const int wave = tid >> 6;
    const int lane = tid & 63;
    const int wr   = (wave & 1) * 64;        // wave row offset within 128-tile
    const int wc   = (wave >> 1) * 64;       // wave col offset
    const int lm   = lane & 15;              // m (A) / n (B) / col (C)
    const int kq   = lane >> 4;              // k-quad
    const int kb   = kq * 8;                 // k base for frags

    // staging assignments
    const int aK = (tid & 7) * 4;            // A: k offset (float4 along k)
    const int aR = tid >> 3;                 // A: row base (0..31), rows aR+32*i
    const int bC = (tid & 31) * 4;           // B: col offset (float4 along cols)
    const int bK = (tid >> 5) * 4;           // B: k row base (4 rows)

    f32x4 acc[4][4];
    #pragma unroll
    for (int i = 0; i < 4; i++)
        #pragma unroll
        for (int j = 0; j < 4; j++)
            acc[i][j] = (f32x4){0.f, 0.f, 0.f, 0.f};

    for (int k0 = 0; k0 < g; k0 += BK) {
        // ---- stage A: M[row0+r][k0+aK .. +3] -> sA (zero-pad outside group) ----
        #pragma unroll
        for (int i = 0; i < 4; i++) {
            int r = aR + 32 * i;
            float4 v = make_float4(0.f, 0.f, 0.f, 0.f);
            if ((row0 + r) < g && (k0 + aK) < g)
                v = *(const float4*)(M + (size_t)(row0 + r) * g + (k0 + aK));
            bf16x4 w;
            w[0] = (bf16)v.x; w[1] = (bf16)v.y; w[2] = (bf16)v.z; w[3] = (bf16)v.w;
            *(bf16x4*)&sA[r][aK] = w;
        }

        // ---- stage B: X[s+k0+bK+j][colb+bC .. +3] -> sB transposed ----
        float4 xv[4];
        #pragma unroll
        for (int j = 0; j < 4; j++)
            xv[j] = *(const float4*)(x + (size_t)(s + k0 + bK + j) * NCOL + colb + bC);
        #pragma unroll
        for (int cc = 0; cc < 4; cc++) {
            int lc = bC + cc;
            bf16x4 w;
            #pragma unroll
            for (int j = 0; j < 4; j++)
                w[j] = (bf16)(((const float*)&xv[j])[cc]);
            *(bf16x4*)&sB[lc][bK ^ (((lc >> 2) & 3) << 3)] = w;
        }

        __syncthreads();

        // ---- fragments + MFMA ----
        bf16x8 af[4], bfr[4];
        #pragma unroll
        for (int i = 0; i < 4; i++)
            af[i] = *(const bf16x8*)&sA[wr + i * 16 + lm][kb];
        #pragma unroll
        for (int j = 0; j < 4; j++) {
            int lc = wc + j * 16 + lm;
            bfr[j] = *(const bf16x8*)&sB[lc][kb ^ (((lc >> 2) & 3) << 3)];
        }
        #pragma unroll
        for (int i = 0; i < 4; i++)
            #pragma unroll
            for (int j = 0; j < 4; j++)
                acc[i][j] = __builtin_amdgcn_mfma_f32_16x16x32_bf16(af[i], bfr[j], acc[i][j], 0, 0, 0);

        __syncthreads();
    }

    // ---- epilogue: C/D layout col=lane&15, row=(lane>>4)*4+reg ----
    #pragma unroll
    for (int i = 0; i < 4; i++) {
        #pragma unroll
        for (int r = 0; r < 4; r++) {
            int row = row0 + wr + i * 16 + kq * 4 + r;
            if (row < g) {
                float* orow = out + (size_t)(s + row) * NCOL + colb + wc;
                #pragma unroll
                for (int j = 0; j < 4; j++)
                    orow[j * 16 + lm] = acc[i][j][r];
            }
        }
    }
}

extern "C" void kernel_launch(void* const* d_in, const int* in_sizes, int n_in,
                              void* d_out, int out_size, void* d_ws, size_t ws_size,
                              hipStream_t stream)
{
    const float* x = (const float*)d_in[0];
    MatPtrs mp;
    for (int i = 0; i < NG; i++) mp.p[i] = (const float*)d_in[1 + i];
    float* out = (float*)d_out;

    dim3 grid(NTILES, NCOL / BN);   // (23, 84): row-tiles fastest for L2 X sharing
    dim3 block(256);
    matapply_kernel<<<grid, block, 0, stream>>>(x, mp, out);
}

// Round 2
// 199.945 us; speedup vs baseline: 1.0459x; 1.0459x over previous
//
#include <hip/hip_runtime.h>
#include <hip/hip_bf16.h>

#define NCOL 10752   // 512*21
#define NROW 2048
#define NG 15
#define NTILES 23

typedef __bf16 bf16;
typedef __attribute__((ext_vector_type(8))) __bf16 bf16x8;
typedef __attribute__((ext_vector_type(4))) __bf16 bf16x4;
typedef __attribute__((ext_vector_type(4))) float f32x4;

__constant__ int c_gsize[NG]  = {64,128,256,96,160,224,192,288,320,112,80,48,32,16,32};
__constant__ int c_gstart[NG] = {0,64,192,448,544,704,928,1120,1408,1728,1840,1920,1968,2000,2016};
// tiles sorted by descending group size: long blocks dispatch first (smaller tail),
// same-group row-tiles adjacent (L2 reuse of identical X block at same colb)
__constant__ int c_tgrp[NTILES] = {8,8,8,7,7,7,2,2,5,5,6,6,4,4,1,9,3,10,0,11,12,14,13};
__constant__ int c_trow[NTILES] = {0,128,256,0,128,256,0,128,0,128,0,128,0,128,0,0,0,0,0,0,0,0,0};

struct MatPtrs { const float* p[NG]; };

constexpr int BM = 128, BN = 128, BK = 32, BKp = 40;

__global__ __launch_bounds__(256)
void matapply_kernel(const float* __restrict__ x, MatPtrs mats, float* __restrict__ out)
{
    // double-buffered: 2 * (128*40 + 128*40) * 2B = 40 KB -> 4 blocks/CU
    __shared__ bf16 sA[2][BM][BKp];   // M tile: [row][k]
    __shared__ bf16 sB[2][BN][BKp];   // X tile transposed: [col][k], k XOR-swizzled

    const int tid    = threadIdx.x;
    const int tileid = blockIdx.x;
    const int colb   = blockIdx.y * BN;

    const int grp  = c_tgrp[tileid];
    const int row0 = c_trow[tileid];
    const int g    = c_gsize[grp];
    const int s    = c_gstart[grp];
    const float* __restrict__ M = mats.p[grp];

    const int wave = tid >> 6;
    const int lane = tid & 63;
    const int wr   = (wave & 1) * 64;
    const int wc   = (wave >> 1) * 64;
    const int lm   = lane & 15;
    const int kq   = lane >> 4;
    const int kb   = kq * 8;

    // staging assignments
    const int aK = (tid & 7) * 4;            // A: k offset (float4 along k)
    const int aR = tid >> 3;                 // A: row base (0..31), rows aR+32*i
    const int bC = (tid & 31) * 4;           // B: col offset (float4 along cols)
    const int bK = (tid >> 5) * 4;           // B: k row base (4 rows)

    const int nIter = (g + BK - 1) / BK;

    f32x4 acc[4][4];
    #pragma unroll
    for (int i = 0; i < 4; i++)
        #pragma unroll
        for (int j = 0; j < 4; j++)
            acc[i][j] = (f32x4){0.f, 0.f, 0.f, 0.f};

    float4 av[4], xv[4];

    // ---- prologue: load iter 0 into regs ----
    #pragma unroll
    for (int i = 0; i < 4; i++) {
        int r = aR + 32 * i;
        av[i] = make_float4(0.f, 0.f, 0.f, 0.f);
        if ((row0 + r) < g && aK < g)
            av[i] = *(const float4*)(M + (size_t)(row0 + r) * g + aK);
    }
    #pragma unroll
    for (int j = 0; j < 4; j++)
        xv[j] = *(const float4*)(x + (size_t)(s + bK + j) * NCOL + colb + bC);

    // store iter 0 into buf 0
    #pragma unroll
    for (int i = 0; i < 4; i++) {
        int r = aR + 32 * i;
        bf16x4 w;
        w[0] = (bf16)av[i].x; w[1] = (bf16)av[i].y; w[2] = (bf16)av[i].z; w[3] = (bf16)av[i].w;
        *(bf16x4*)&sA[0][r][aK] = w;
    }
    #pragma unroll
    for (int cc = 0; cc < 4; cc++) {
        int lc = bC + cc;
        bf16x4 w;
        #pragma unroll
        for (int j = 0; j < 4; j++)
            w[j] = (bf16)(((const float*)&xv[j])[cc]);
        *(bf16x4*)&sB[0][lc][bK ^ (((lc >> 2) & 3) << 3)] = w;
    }
    __syncthreads();

    for (int it = 0; it < nIter; ++it) {
        const int cur = it & 1;
        const bool more = (it + 1) < nIter;

        // ---- issue global loads for next iter (in flight during compute) ----
        if (more) {
            const int k0 = (it + 1) * BK;
            #pragma unroll
            for (int i = 0; i < 4; i++) {
                int r = aR + 32 * i;
                av[i] = make_float4(0.f, 0.f, 0.f, 0.f);
                if ((row0 + r) < g && (k0 + aK) < g)
                    av[i] = *(const float4*)(M + (size_t)(row0 + r) * g + (k0 + aK));
            }
            #pragma unroll
            for (int j = 0; j < 4; j++)
                xv[j] = *(const float4*)(x + (size_t)(s + k0 + bK + j) * NCOL + colb + bC);
        }

        // ---- compute from buf[cur] ----
        bf16x8 af[4], bfr[4];
        #pragma unroll
        for (int i = 0; i < 4; i++)
            af[i] = *(const bf16x8*)&sA[cur][wr + i * 16 + lm][kb];
        #pragma unroll
        for (int j = 0; j < 4; j++) {
            int lc = wc + j * 16 + lm;
            bfr[j] = *(const bf16x8*)&sB[cur][lc][kb ^ (((lc >> 2) & 3) << 3)];
        }
        #pragma unroll
        for (int i = 0; i < 4; i++)
            #pragma unroll
            for (int j = 0; j < 4; j++)
                acc[i][j] = __builtin_amdgcn_mfma_f32_16x16x32_bf16(af[i], bfr[j], acc[i][j], 0, 0, 0);

        // ---- drain loads, stage next tile into buf[1-cur], one barrier ----
        if (more) {
            const int nxt = 1 - cur;
            #pragma unroll
            for (int i = 0; i < 4; i++) {
                int r = aR + 32 * i;
                bf16x4 w;
                w[0] = (bf16)av[i].x; w[1] = (bf16)av[i].y; w[2] = (bf16)av[i].z; w[3] = (bf16)av[i].w;
                *(bf16x4*)&sA[nxt][r][aK] = w;
            }
            #pragma unroll
            for (int cc = 0; cc < 4; cc++) {
                int lc = bC + cc;
                bf16x4 w;
                #pragma unroll
                for (int j = 0; j < 4; j++)
                    w[j] = (bf16)(((const float*)&xv[j])[cc]);
                *(bf16x4*)&sB[nxt][lc][bK ^ (((lc >> 2) & 3) << 3)] = w;
            }
            __syncthreads();
        }
    }

    // ---- epilogue: C/D layout col=lane&15, row=(lane>>4)*4+reg ----
    #pragma unroll
    for (int i = 0; i < 4; i++) {
        #pragma unroll
        for (int r = 0; r < 4; r++) {
            int row = row0 + wr + i * 16 + kq * 4 + r;
            if (row < g) {
                float* orow = out + (size_t)(s + row) * NCOL + colb + wc;
                #pragma unroll
                for (int j = 0; j < 4; j++)
                    orow[j * 16 + lm] = acc[i][j][r];
            }
        }
    }
}

extern "C" void kernel_launch(void* const* d_in, const int* in_sizes, int n_in,
                              void* d_out, int out_size, void* d_ws, size_t ws_size,
                              hipStream_t stream)
{
    const float* x = (const float*)d_in[0];
    MatPtrs mp;
    for (int i = 0; i < NG; i++) mp.p[i] = (const float*)d_in[1 + i];
    float* out = (float*)d_out;

    dim3 grid(NTILES, NCOL / BN);   // (23, 84)
    dim3 block(256);
    matapply_kernel<<<grid, block, 0, stream>>>(x, mp, out);
}

// Round 3
// 192.799 us; speedup vs baseline: 1.0847x; 1.0371x over previous
//
#include <hip/hip_runtime.h>
#include <hip/hip_bf16.h>

#define NCOL 10752   // 512*21
#define NROW 2048
#define NG 15
#define NTILES 23

typedef __bf16 bf16;
typedef __attribute__((ext_vector_type(8))) __bf16 bf16x8;
typedef __attribute__((ext_vector_type(4))) __bf16 bf16x4;
typedef __attribute__((ext_vector_type(4))) float f32x4;

__constant__ int c_gsize[NG]  = {64,128,256,96,160,224,192,288,320,112,80,48,32,16,32};
__constant__ int c_gstart[NG] = {0,64,192,448,544,704,928,1120,1408,1728,1840,1920,1968,2000,2016};
// tiles sorted by descending group size; grid.x = colb so the 84 blocks of one
// tile-row stream ADJACENT 512B segments of the same k-rows (DRAM page coalescing),
// and same-group tile-rows are adjacent in y for L3 reuse of the X stripe.
__constant__ int c_tgrp[NTILES] = {8,8,8,7,7,7,2,2,5,5,6,6,4,4,1,9,3,10,0,11,12,14,13};
__constant__ int c_trow[NTILES] = {0,128,256,0,128,256,0,128,0,128,0,128,0,128,0,0,0,0,0,0,0,0,0};

struct MatPtrs { const float* p[NG]; };

constexpr int BM = 128, BN = 128, BK = 32, BKp = 40;

__global__ __launch_bounds__(256)
void matapply_kernel(const float* __restrict__ x, MatPtrs mats, float* __restrict__ out)
{
    // double-buffered: 2 * (128*40 + 128*40) * 2B = 40 KB -> 4 blocks/CU
    __shared__ bf16 sA[2][BM][BKp];   // M tile: [row][k]
    __shared__ bf16 sB[2][BN][BKp];   // X tile transposed: [col][k], k XOR-swizzled

    const int tid    = threadIdx.x;
    const int colb   = blockIdx.x * BN;      // fastest dim: adjacent blocks = adjacent cols
    const int tileid = blockIdx.y;

    const int grp  = c_tgrp[tileid];
    const int row0 = c_trow[tileid];
    const int g    = c_gsize[grp];
    const int s    = c_gstart[grp];
    const float* __restrict__ M = mats.p[grp];

    const int wave = tid >> 6;
    const int lane = tid & 63;
    const int wr   = (wave & 1) * 64;
    const int wc   = (wave >> 1) * 64;
    const int lm   = lane & 15;
    const int kq   = lane >> 4;
    const int kb   = kq * 8;

    // staging assignments
    const int aK = (tid & 7) * 4;            // A: k offset (float4 along k)
    const int aR = tid >> 3;                 // A: row base (0..31), rows aR+32*i
    const int bC = (tid & 31) * 4;           // B: col offset (float4 along cols)
    const int bK = (tid >> 5) * 4;           // B: k row base (4 rows)

    const int nIter = (g + BK - 1) / BK;

    f32x4 acc[4][4];
    #pragma unroll
    for (int i = 0; i < 4; i++)
        #pragma unroll
        for (int j = 0; j < 4; j++)
            acc[i][j] = (f32x4){0.f, 0.f, 0.f, 0.f};

    float4 av[4], xv[4];

    // ---- prologue: load iter 0 into regs ----
    #pragma unroll
    for (int i = 0; i < 4; i++) {
        int r = aR + 32 * i;
        av[i] = make_float4(0.f, 0.f, 0.f, 0.f);
        if ((row0 + r) < g && aK < g)
            av[i] = *(const float4*)(M + (size_t)(row0 + r) * g + aK);
    }
    #pragma unroll
    for (int j = 0; j < 4; j++)
        xv[j] = *(const float4*)(x + (size_t)(s + bK + j) * NCOL + colb + bC);

    // store iter 0 into buf 0
    #pragma unroll
    for (int i = 0; i < 4; i++) {
        int r = aR + 32 * i;
        bf16x4 w;
        w[0] = (bf16)av[i].x; w[1] = (bf16)av[i].y; w[2] = (bf16)av[i].z; w[3] = (bf16)av[i].w;
        *(bf16x4*)&sA[0][r][aK] = w;
    }
    #pragma unroll
    for (int cc = 0; cc < 4; cc++) {
        int lc = bC + cc;
        bf16x4 w;
        #pragma unroll
        for (int j = 0; j < 4; j++)
            w[j] = (bf16)(((const float*)&xv[j])[cc]);
        *(bf16x4*)&sB[0][lc][bK ^ (((lc >> 2) & 3) << 3)] = w;
    }
    __syncthreads();

    for (int it = 0; it < nIter; ++it) {
        const int cur = it & 1;
        const bool more = (it + 1) < nIter;

        // ---- issue global loads for next iter (in flight during compute) ----
        if (more) {
            const int k0 = (it + 1) * BK;
            #pragma unroll
            for (int i = 0; i < 4; i++) {
                int r = aR + 32 * i;
                av[i] = make_float4(0.f, 0.f, 0.f, 0.f);
                if ((row0 + r) < g && (k0 + aK) < g)
                    av[i] = *(const float4*)(M + (size_t)(row0 + r) * g + (k0 + aK));
            }
            #pragma unroll
            for (int j = 0; j < 4; j++)
                xv[j] = *(const float4*)(x + (size_t)(s + k0 + bK + j) * NCOL + colb + bC);
        }

        // ---- compute from buf[cur] ----
        bf16x8 af[4], bfr[4];
        #pragma unroll
        for (int i = 0; i < 4; i++)
            af[i] = *(const bf16x8*)&sA[cur][wr + i * 16 + lm][kb];
        #pragma unroll
        for (int j = 0; j < 4; j++) {
            int lc = wc + j * 16 + lm;
            bfr[j] = *(const bf16x8*)&sB[cur][lc][kb ^ (((lc >> 2) & 3) << 3)];
        }
        #pragma unroll
        for (int i = 0; i < 4; i++)
            #pragma unroll
            for (int j = 0; j < 4; j++)
                acc[i][j] = __builtin_amdgcn_mfma_f32_16x16x32_bf16(af[i], bfr[j], acc[i][j], 0, 0, 0);

        // ---- drain loads, stage next tile into buf[1-cur], one barrier ----
        if (more) {
            const int nxt = 1 - cur;
            #pragma unroll
            for (int i = 0; i < 4; i++) {
                int r = aR + 32 * i;
                bf16x4 w;
                w[0] = (bf16)av[i].x; w[1] = (bf16)av[i].y; w[2] = (bf16)av[i].z; w[3] = (bf16)av[i].w;
                *(bf16x4*)&sA[nxt][r][aK] = w;
            }
            #pragma unroll
            for (int cc = 0; cc < 4; cc++) {
                int lc = bC + cc;
                bf16x4 w;
                #pragma unroll
                for (int j = 0; j < 4; j++)
                    w[j] = (bf16)(((const float*)&xv[j])[cc]);
                *(bf16x4*)&sB[nxt][lc][bK ^ (((lc >> 2) & 3) << 3)] = w;
            }
            __syncthreads();
        }
    }

    // ---- epilogue: C/D layout col=lane&15, row=(lane>>4)*4+reg ----
    #pragma unroll
    for (int i = 0; i < 4; i++) {
        #pragma unroll
        for (int r = 0; r < 4; r++) {
            int row = row0 + wr + i * 16 + kq * 4 + r;
            if (row < g) {
                float* orow = out + (size_t)(s + row) * NCOL + colb + wc;
                #pragma unroll
                for (int j = 0; j < 4; j++)
                    orow[j * 16 + lm] = acc[i][j][r];
            }
        }
    }
}

extern "C" void kernel_launch(void* const* d_in, const int* in_sizes, int n_in,
                              void* d_out, int out_size, void* d_ws, size_t ws_size,
                              hipStream_t stream)
{
    const float* x = (const float*)d_in[0];
    MatPtrs mp;
    for (int i = 0; i < NG; i++) mp.p[i] = (const float*)d_in[1 + i];
    float* out = (float*)d_out;

    dim3 grid(NCOL / BN, NTILES);   // (84, 23): colb fastest for DRAM page coalescing
    dim3 block(256);
    matapply_kernel<<<grid, block, 0, stream>>>(x, mp, out);
}